// Round 1
// baseline (344.807 us; speedup 1.0000x reference)
//
#include <hip/hip_runtime.h>
#include <hip/hip_bf16.h>

// ---------------------------------------------------------------------------
// TinyMNISTNet: out = relu(x @ Wq1^T + b1) @ Wq2^T + b2, ternarized weights.
// x: [65536,784] fp32; W1: [64,784]; b1:[64]; W2:[10,64]; b2:[10]; out fp32 [65536,10].
//
// R3: (a) setup collapsed to ONE single-block 1024-thread kernel (no memset,
//     no f64 atomics, alphas computed in-kernel) — 3 dispatches -> 1;
//     (b) fused K-loop bf16 conversion via v_cvt_pk_bf16_f32 (4 instrs/step
//     instead of ~32 VALU of hand-rolled RNE).
// ---------------------------------------------------------------------------

typedef __attribute__((ext_vector_type(4))) float f32x4;
typedef __attribute__((ext_vector_type(8))) short s16x8;
typedef __attribute__((ext_vector_type(4))) short s16x4;
typedef __attribute__((ext_vector_type(2))) unsigned int u32x2;

#define K1 784
#define K1_PAD 800          // 25 K-steps of 32
#define NHID 64
#define NOUT 10

// round-to-nearest-even f32 -> bf16 bits (finite inputs) — epilogue use only
static __device__ __forceinline__ unsigned short f2bf_rne(float f) {
    unsigned int u = __builtin_bit_cast(unsigned int, f);
    unsigned int r = u + 0x7FFFu + ((u >> 16) & 1u);
    return (unsigned short)(r >> 16);
}

// packed f32x2 -> bf16x2 (RNE), gfx950 HW instruction (no builtin; T12/m240)
static __device__ __forceinline__ unsigned int cvt_pk_bf16(float lo, float hi) {
    unsigned int r;
    asm("v_cvt_pk_bf16_f32 %0, %1, %2" : "=v"(r) : "v"(lo), "v"(hi));
    return r;
}

// block-wide f64 sum for a single 1024-thread (16-wave) block
static __device__ double block_sum1024(double v, double* red) {
    #pragma unroll
    for (int off = 32; off > 0; off >>= 1) v += __shfl_down(v, off, 64);
    const int w = threadIdx.x >> 6;
    const int lane = threadIdx.x & 63;
    __syncthreads();                 // protect red[] reuse across calls
    if (lane == 0) red[w] = v;
    __syncthreads();
    double s = 0.0;
    #pragma unroll
    for (int i = 0; i < 16; ++i) s += red[i];   // broadcast reads
    return s;
}

// ---------------------------------------------------------------------------
// Single-dispatch ternarize: one block, 1024 threads. Pass 1 sums |W| (HBM,
// 200 KB); pass 2 re-reads from L2, quantizes to bf16 sign values, and reduces
// sum/count for alpha. No atomics, no hdr zeroing needed.
// hdr layout (doubles): [0]=alpha1 [1]=alpha2
// ---------------------------------------------------------------------------
__global__ __launch_bounds__(1024) void tern_all_kernel(
    const float* __restrict__ W1, const float* __restrict__ W2,
    unsigned short* __restrict__ W1q, unsigned short* __restrict__ W2q,
    double* __restrict__ hdr)
{
    __shared__ double red[16];
    const int tid = threadIdx.x;

    // ---- pass 1: sum |W1|, sum |W2| ----
    double s1 = 0.0;
    for (int i = tid; i < NHID * K1; i += 1024)
        s1 += (double)fabsf(W1[i]);
    double s2 = 0.0;
    for (int i = tid; i < NOUT * NHID; i += 1024)
        s2 += (double)fabsf(W2[i]);
    s1 = block_sum1024(s1, red);
    s2 = block_sum1024(s2, red);

    const float delta1 = (float)(0.7 * s1 / (double)(NHID * K1));
    const float delta2 = (float)(0.7 * s2 / (double)(NOUT * NHID));

    // ---- pass 2: quantize W1 -> [64][800] padded bf16 signs ----
    double sm1 = 0.0, cn1 = 0.0;
    for (int i = tid; i < NHID * K1_PAD; i += 1024) {
        int n = i / K1_PAD;
        int k = i - n * K1_PAD;
        unsigned short v = 0;
        if (k < K1) {
            float w = W1[n * K1 + k];
            float a = fabsf(w);
            if (a > delta1) { v = (w > 0.0f) ? 0x3F80u : 0xBF80u; sm1 += (double)a; cn1 += 1.0; }
        }
        W1q[i] = v;
    }

    // ---- quantize W2 -> [16][64] (rows 10..15 zero) ----
    double sm2 = 0.0, cn2 = 0.0;
    for (int i = tid; i < 16 * NHID; i += 1024) {
        int n = i >> 6;
        int k = i & 63;
        unsigned short v = 0;
        if (n < NOUT) {
            float w = W2[n * NHID + k];
            float a = fabsf(w);
            if (a > delta2) { v = (w > 0.0f) ? 0x3F80u : 0xBF80u; sm2 += (double)a; cn2 += 1.0; }
        }
        W2q[i] = v;
    }

    sm1 = block_sum1024(sm1, red);
    cn1 = block_sum1024(cn1, red);
    sm2 = block_sum1024(sm2, red);
    cn2 = block_sum1024(cn2, red);
    if (tid == 0) {
        hdr[0] = sm1 / fmax(cn1, 1.0);
        hdr[1] = sm2 / fmax(cn2, 1.0);
    }
}

// ---------------------------------------------------------------------------
// Fused 2-layer kernel. 256 threads = 4 waves; each wave: 16 batch rows x all
// 64 hidden features, then 16x10 outputs. Grid: nrows/64.
//
// Per K-step (32 floats/row), each wave stages its 16x32 fp32 tile:
//   sweep0: lane i loads rows m0+(i>>3), 16B at float (i&7)*4   -> 8x128B txns
//   sweep1: same for rows m0+8+(i>>3)
// convert to bf16 (v_cvt_pk_bf16_f32), write to wave-private LDS (contiguous,
// conflict-free), read back MFMA A-fragments (lane: row=lane&15, k=quad*8).
// Double-buffered; next chunk's global loads issue one full iteration ahead.
//
// MFMA 16x16x32 bf16 layouts (m89/m91/m120-verified):
//   A[m=lane&15][k=quad*8+j], B[n=lane&15][k=quad*8+j], C/D: col=lane&15, row=quad*4+reg
// ---------------------------------------------------------------------------
__global__ __launch_bounds__(256) void fused_kernel(
    const float* __restrict__ x,
    const float* __restrict__ b1,
    const float* __restrict__ b2,
    const short* __restrict__ W1q,   // [64][800] bf16 signs
    const short* __restrict__ W2q,   // [16][64]  bf16 signs
    const double* __restrict__ hdr,
    float* __restrict__ out)
{
    const int tid  = threadIdx.x;
    const int wave = tid >> 6;
    const int lane = tid & 63;
    const int low  = lane & 15;
    const int quad = lane >> 4;

    const int m0 = blockIdx.x * 64 + wave * 16;

    // staging-load role: 8 lanes per row, 16B per lane (contiguous 128B/row)
    const int srow = lane >> 3;      // 0..7
    const int scol = lane & 7;       // *4 floats = *16 bytes
    const float* g0 = x + (size_t)(m0 + srow) * K1 + scol * 4;
    const float* g1 = x + (size_t)(m0 + 8 + srow) * K1 + scol * 4;

    // wave-private double-buffered A-stage: [wave][buf][row 16][k 32] bf16 = 1KB/buf
    __shared__ __align__(16) unsigned short stage[4][2][16][32];
    __shared__ __align__(16) unsigned short h_lds[4][16][72];  // layer-2 A staging

    const short* wbase = W1q + (size_t)low * K1_PAD + quad * 8;

    f32x4 acc[4];
    #pragma unroll
    for (int nt = 0; nt < 4; ++nt) acc[nt] = (f32x4){0.f, 0.f, 0.f, 0.f};

    const f32x4 zero4 = (f32x4){0.f, 0.f, 0.f, 0.f};

    // prologue: load chunk 0
    f32x4 c0 = *(const f32x4*)(g0);
    f32x4 c1 = *(const f32x4*)(g1);

    int buf = 0;
    for (int ks = 0; ks < 25; ++ks) {
        // prefetch next chunk (full iteration of latency hiding)
        f32x4 n0 = zero4, n1 = zero4;
        if (ks < 24) {
            const int kf = (ks + 1) * 32 + scol * 4;
            if (kf < K1) {               // tail chunk 24: only scol<4 valid
                n0 = *(const f32x4*)(g0 + (ks + 1) * 32);
                n1 = *(const f32x4*)(g1 + (ks + 1) * 32);
            }
        }

        // convert current chunk -> bf16 (packed HW cvt), stash to LDS
        u32x2 p0, p1;
        p0[0] = cvt_pk_bf16(c0[0], c0[1]);
        p0[1] = cvt_pk_bf16(c0[2], c0[3]);
        p1[0] = cvt_pk_bf16(c1[0], c1[1]);
        p1[1] = cvt_pk_bf16(c1[2], c1[3]);
        *(u32x2*)&stage[wave][buf][srow][scol * 4]     = p0;
        *(u32x2*)&stage[wave][buf][8 + srow][scol * 4] = p1;

        // wave-private LDS write->cross-lane read: drain DS pipe explicitly
        __asm__ volatile("s_waitcnt lgkmcnt(0)" ::: "memory");

        s16x8 a = *(const s16x8*)&stage[wave][buf][low][quad * 8];
        const short* wk = wbase + ks * 32;
        #pragma unroll
        for (int nt = 0; nt < 4; ++nt) {
            s16x8 b = *(const s16x8*)(wk + (size_t)nt * 16 * K1_PAD);
            acc[nt] = __builtin_amdgcn_mfma_f32_16x16x32_bf16(a, b, acc[nt], 0, 0, 0);
        }

        c0 = n0; c1 = n1; buf ^= 1;
    }

    // ---- epilogue 1: alpha1*acc + b1, relu, bf16 -> LDS (C-layout -> A-layout) ----
    const float alpha1 = (float)hdr[0];
    const float alpha2 = (float)hdr[1];

    #pragma unroll
    for (int nt = 0; nt < 4; ++nt) {
        const int n = nt * 16 + low;
        const float bias = b1[n];
        #pragma unroll
        for (int r = 0; r < 4; ++r) {
            float hv = fmaxf(0.0f, fmaf(alpha1, acc[nt][r], bias));
            h_lds[wave][quad * 4 + r][n] = f2bf_rne(hv);
        }
    }
    __asm__ volatile("s_waitcnt lgkmcnt(0)" ::: "memory");

    // ---- layer 2: [16x64] x [64x16] via 2 MFMA steps ----
    s16x8 a0 = *(const s16x8*)(&h_lds[wave][low][quad * 8]);
    s16x8 a1 = *(const s16x8*)(&h_lds[wave][low][32 + quad * 8]);
    s16x8 w0 = *(const s16x8*)(W2q + low * 64 + quad * 8);
    s16x8 w1 = *(const s16x8*)(W2q + low * 64 + 32 + quad * 8);

    f32x4 acc2 = (f32x4){0.f, 0.f, 0.f, 0.f};
    acc2 = __builtin_amdgcn_mfma_f32_16x16x32_bf16(a0, w0, acc2, 0, 0, 0);
    acc2 = __builtin_amdgcn_mfma_f32_16x16x32_bf16(a1, w1, acc2, 0, 0, 0);

    // ---- epilogue 2: alpha2*acc2 + b2, store fp32 ----
    if (low < NOUT) {
        const float bias2 = b2[low];
        #pragma unroll
        for (int r = 0; r < 4; ++r) {
            const int row = m0 + quad * 4 + r;
            out[(size_t)row * NOUT + low] = fmaf(alpha2, acc2[r], bias2);
        }
    }
}

// ---------------------------------------------------------------------------
extern "C" void kernel_launch(void* const* d_in, const int* in_sizes, int n_in,
                              void* d_out, int out_size, void* d_ws, size_t ws_size,
                              hipStream_t stream) {
    const float* x  = (const float*)d_in[0];
    const float* W1 = (const float*)d_in[1];
    const float* b1 = (const float*)d_in[2];
    const float* W2 = (const float*)d_in[3];
    const float* b2 = (const float*)d_in[4];
    float* out = (float*)d_out;

    const int nrows = in_sizes[0] / K1;   // 65536

    // ws layout: hdr 2 doubles (64B aligned block) | W1q [64*800] bf16 | W2q [16*64] bf16
    double* hdr = (double*)d_ws;
    unsigned short* W1q = (unsigned short*)((char*)d_ws + 64);
    unsigned short* W2q = W1q + NHID * K1_PAD;

    tern_all_kernel<<<1, 1024, 0, stream>>>(W1, W2, W1q, W2q, hdr);

    const int nblocks = nrows / 64;       // 64 rows per block (16 per wave)
    fused_kernel<<<nblocks, 256, 0, stream>>>(x, b1, b2, (const short*)W1q,
                                              (const short*)W2q, hdr, out);
}

// Round 2
// 312.212 us; speedup vs baseline: 1.1044x; 1.1044x over previous
//
#include <hip/hip_runtime.h>
#include <hip/hip_bf16.h>

// ---------------------------------------------------------------------------
// TinyMNISTNet: out = relu(x @ Wq1^T + b1) @ Wq2^T + b2, ternarized weights.
// x: [65536,784] fp32; W1: [64,784]; b1:[64]; W2:[10,64]; b2:[10]; out fp32 [65536,10].
//
// R4: (a) setup back to PARALLEL (R3's single-block version cost ~50us on one
//     CU) but now atomic-free and memset-free: kernel A writes per-block
//     partial sums, kernel B (1 block per W1 row) quantizes + writes per-row
//     sm/cn partials; alpha1 reduction folded into the fused kernel epilogue.
//     4 dispatches -> 3, no serial-CU work.
//     (b) fused K-loop: W1q B-fragments software-pipelined one step ahead in
//     registers, so the lgkmcnt(0) barrier no longer exposes ~200cy L2 latency
//     per K-step.
// ---------------------------------------------------------------------------

typedef __attribute__((ext_vector_type(4))) float f32x4;
typedef __attribute__((ext_vector_type(8))) short s16x8;
typedef __attribute__((ext_vector_type(2))) unsigned int u32x2;

#define K1 784
#define K1_PAD 800          // 25 K-steps of 32
#define NHID 64
#define NOUT 10

// round-to-nearest-even f32 -> bf16 bits (finite inputs) — epilogue use only
static __device__ __forceinline__ unsigned short f2bf_rne(float f) {
    unsigned int u = __builtin_bit_cast(unsigned int, f);
    unsigned int r = u + 0x7FFFu + ((u >> 16) & 1u);
    return (unsigned short)(r >> 16);
}

// packed f32x2 -> bf16x2 (RNE), gfx950 HW instruction (no builtin; T12/m240)
static __device__ __forceinline__ unsigned int cvt_pk_bf16(float lo, float hi) {
    unsigned int r;
    asm("v_cvt_pk_bf16_f32 %0, %1, %2" : "=v"(r) : "v"(lo), "v"(hi));
    return r;
}

// block-wide f64 sum for 256-thread blocks (4 waves); result valid in all threads
static __device__ double block_sum256(double v, double* red) {
    #pragma unroll
    for (int off = 32; off > 0; off >>= 1) v += __shfl_down(v, off, 64);
    const int w = threadIdx.x >> 6;
    const int lane = threadIdx.x & 63;
    __syncthreads();                 // protect red[] reuse across calls
    if (lane == 0) red[w] = v;
    __syncthreads();
    return red[0] + red[1] + red[2] + red[3];
}

// ---------------------------------------------------------------------------
// ws layout (see kernel_launch):
//   p1[64]   : per-block partial sum|W1|
//   psm[64]  : per-row sum of kept |W1| (written by quant kernel)
//   pcn[64]  : per-row kept count
//   p2,a2    : sum|W2| (exact), alpha2 (exact)
//   W1q      : [64][800] bf16 sign values
//   W2q      : [16][64]  bf16 sign values
// ---------------------------------------------------------------------------

__global__ __launch_bounds__(256) void tern_sum_kernel(
    const float* __restrict__ W1, const float* __restrict__ W2,
    double* __restrict__ p1, double* __restrict__ p2)
{
    __shared__ double red[4];
    const int gid = blockIdx.x * 256 + threadIdx.x;

    // W1: 50176 floats = 12544 f32x4; 64 blocks x 256 threads = 16384 slots
    double s = 0.0;
    if (gid < (NHID * K1) / 4) {
        f32x4 v = ((const f32x4*)W1)[gid];
        s = (double)fabsf(v[0]) + (double)fabsf(v[1])
          + (double)fabsf(v[2]) + (double)fabsf(v[3]);
    }
    s = block_sum256(s, red);
    if (threadIdx.x == 0) p1[blockIdx.x] = s;

    if (blockIdx.x == 0) {
        // W2: 640 floats = 160 f32x4
        double s2 = 0.0;
        if (threadIdx.x < (NOUT * NHID) / 4) {
            f32x4 v = ((const f32x4*)W2)[threadIdx.x];
            s2 = (double)fabsf(v[0]) + (double)fabsf(v[1])
               + (double)fabsf(v[2]) + (double)fabsf(v[3]);
        }
        s2 = block_sum256(s2, red);
        if (threadIdx.x == 0) p2[0] = s2;
    }
}

__global__ __launch_bounds__(256) void tern_quant_kernel(
    const float* __restrict__ W1, const float* __restrict__ W2,
    unsigned short* __restrict__ W1q, unsigned short* __restrict__ W2q,
    const double* __restrict__ p1, const double* __restrict__ p2,
    double* __restrict__ psm, double* __restrict__ pcn,
    double* __restrict__ a2)
{
    __shared__ double red[4];

    // reduce the 64 partials -> total sum|W1| (all blocks redundantly, L2-hot)
    double v = (threadIdx.x < 64) ? p1[threadIdx.x] : 0.0;
    const double s1 = block_sum256(v, red);
    const float delta1 = (float)(0.7 * s1 / (double)(NHID * K1));

    // this block quantizes W1 row n -> padded [800] bf16 signs
    const int n = blockIdx.x;
    double sm = 0.0, cn = 0.0;
    for (int k = threadIdx.x; k < K1_PAD; k += 256) {
        unsigned short q = 0;
        if (k < K1) {
            float w = W1[n * K1 + k];
            float a = fabsf(w);
            if (a > delta1) { q = (w > 0.0f) ? 0x3F80u : 0xBF80u; sm += (double)a; cn += 1.0; }
        }
        W1q[n * K1_PAD + k] = q;
    }
    sm = block_sum256(sm, red);
    cn = block_sum256(cn, red);
    if (threadIdx.x == 0) { psm[n] = sm; pcn[n] = cn; }

    if (blockIdx.x == 0) {
        const float delta2 = (float)(0.7 * p2[0] / (double)(NOUT * NHID));
        double sm2 = 0.0, cn2 = 0.0;
        for (int i = threadIdx.x; i < 16 * NHID; i += 256) {
            int r = i >> 6;
            int k = i & 63;
            unsigned short q = 0;
            if (r < NOUT) {
                float w = W2[r * NHID + k];
                float a = fabsf(w);
                if (a > delta2) { q = (w > 0.0f) ? 0x3F80u : 0xBF80u; sm2 += (double)a; cn2 += 1.0; }
            }
            W2q[i] = q;
        }
        sm2 = block_sum256(sm2, red);
        cn2 = block_sum256(cn2, red);
        if (threadIdx.x == 0) a2[0] = sm2 / fmax(cn2, 1.0);
    }
}

// ---------------------------------------------------------------------------
// Fused 2-layer kernel. 256 threads = 4 waves; each wave: 16 batch rows x all
// 64 hidden features, then 16x10 outputs. Grid: nrows/64.
//
// Per K-step (32 floats/row), each wave stages its 16x32 fp32 tile:
//   sweep0: lane i loads rows m0+(i>>3), 16B at float (i&7)*4   -> 8x128B txns
//   sweep1: same for rows m0+8+(i>>3)
// convert to bf16 (v_cvt_pk_bf16_f32), write to wave-private LDS (contiguous,
// conflict-free), read back MFMA A-fragments (lane: row=lane&15, k=quad*8).
// x AND W1q-B-fragments double-buffered in registers; next step's loads issue
// one full iteration ahead (before the lgkmcnt barrier pins the DS pipe).
//
// MFMA 16x16x32 bf16 layouts (m89/m91/m120-verified):
//   A[m=lane&15][k=quad*8+j], B[n=lane&15][k=quad*8+j], C/D: col=lane&15, row=quad*4+reg
// ---------------------------------------------------------------------------
__global__ __launch_bounds__(256) void fused_kernel(
    const float* __restrict__ x,
    const float* __restrict__ b1,
    const float* __restrict__ b2,
    const short* __restrict__ W1q,   // [64][800] bf16 signs
    const short* __restrict__ W2q,   // [16][64]  bf16 signs
    const double* __restrict__ psm,  // [64] per-row kept-sum partials
    const double* __restrict__ pcn,  // [64] per-row kept-count partials
    const double* __restrict__ a2,   // [1] alpha2 (exact)
    float* __restrict__ out)
{
    const int tid  = threadIdx.x;
    const int wave = tid >> 6;
    const int lane = tid & 63;
    const int low  = lane & 15;
    const int quad = lane >> 4;

    const int m0 = blockIdx.x * 64 + wave * 16;

    // staging-load role: 8 lanes per row, 16B per lane (contiguous 128B/row)
    const int srow = lane >> 3;      // 0..7
    const int scol = lane & 7;       // *4 floats = *16 bytes
    const float* g0 = x + (size_t)(m0 + srow) * K1 + scol * 4;
    const float* g1 = x + (size_t)(m0 + 8 + srow) * K1 + scol * 4;

    // wave-private double-buffered A-stage: [wave][buf][row 16][k 32] bf16 = 1KB/buf
    __shared__ __align__(16) unsigned short stage[4][2][16][32];
    __shared__ __align__(16) unsigned short h_lds[4][16][72];  // layer-2 A staging

    const short* wbase = W1q + (size_t)low * K1_PAD + quad * 8;

    f32x4 acc[4];
    #pragma unroll
    for (int nt = 0; nt < 4; ++nt) acc[nt] = (f32x4){0.f, 0.f, 0.f, 0.f};

    const f32x4 zero4 = (f32x4){0.f, 0.f, 0.f, 0.f};

    // prologue: x chunk 0 and B fragments for ks=0
    f32x4 c0 = *(const f32x4*)(g0);
    f32x4 c1 = *(const f32x4*)(g1);
    s16x8 bf[4];
    #pragma unroll
    for (int nt = 0; nt < 4; ++nt)
        bf[nt] = *(const s16x8*)(wbase + (size_t)nt * 16 * K1_PAD);

    int buf = 0;
    for (int ks = 0; ks < 25; ++ks) {
        // prefetch next x chunk + next B fragments (full iteration of latency hiding)
        f32x4 n0 = zero4, n1 = zero4;
        s16x8 bn[4];
        if (ks < 24) {
            const short* wn = wbase + (ks + 1) * 32;
            #pragma unroll
            for (int nt = 0; nt < 4; ++nt)
                bn[nt] = *(const s16x8*)(wn + (size_t)nt * 16 * K1_PAD);
            const int kf = (ks + 1) * 32 + scol * 4;
            if (kf < K1) {               // tail chunk 24: only scol<4 valid
                n0 = *(const f32x4*)(g0 + (ks + 1) * 32);
                n1 = *(const f32x4*)(g1 + (ks + 1) * 32);
            }
        }

        // convert current chunk -> bf16 (packed HW cvt), stash to LDS
        u32x2 p0, p1;
        p0[0] = cvt_pk_bf16(c0[0], c0[1]);
        p0[1] = cvt_pk_bf16(c0[2], c0[3]);
        p1[0] = cvt_pk_bf16(c1[0], c1[1]);
        p1[1] = cvt_pk_bf16(c1[2], c1[3]);
        *(u32x2*)&stage[wave][buf][srow][scol * 4]     = p0;
        *(u32x2*)&stage[wave][buf][8 + srow][scol * 4] = p1;

        // wave-private LDS write->cross-lane read: drain DS pipe explicitly
        __asm__ volatile("s_waitcnt lgkmcnt(0)" ::: "memory");

        s16x8 a = *(const s16x8*)&stage[wave][buf][low][quad * 8];
        #pragma unroll
        for (int nt = 0; nt < 4; ++nt)
            acc[nt] = __builtin_amdgcn_mfma_f32_16x16x32_bf16(a, bf[nt], acc[nt], 0, 0, 0);

        #pragma unroll
        for (int nt = 0; nt < 4; ++nt) bf[nt] = bn[nt];
        c0 = n0; c1 = n1; buf ^= 1;
    }

    // ---- alpha1 reduction (per-wave, redundant, L2-hot: 64 doubles each) ----
    double vs = psm[lane], vc = pcn[lane];
    #pragma unroll
    for (int off = 32; off > 0; off >>= 1) {
        vs += __shfl_down(vs, off, 64);
        vc += __shfl_down(vc, off, 64);
    }
    vs = __shfl(vs, 0, 64);
    vc = __shfl(vc, 0, 64);
    const float alpha1 = (float)(vs / fmax(vc, 1.0));
    const float alpha2 = (float)a2[0];

    // ---- epilogue 1: alpha1*acc + b1, relu, bf16 -> LDS (C-layout -> A-layout) ----
    #pragma unroll
    for (int nt = 0; nt < 4; ++nt) {
        const int n = nt * 16 + low;
        const float bias = b1[n];
        #pragma unroll
        for (int r = 0; r < 4; ++r) {
            float hv = fmaxf(0.0f, fmaf(alpha1, acc[nt][r], bias));
            h_lds[wave][quad * 4 + r][n] = f2bf_rne(hv);
        }
    }
    __asm__ volatile("s_waitcnt lgkmcnt(0)" ::: "memory");

    // ---- layer 2: [16x64] x [64x16] via 2 MFMA steps ----
    s16x8 a0 = *(const s16x8*)(&h_lds[wave][low][quad * 8]);
    s16x8 a1 = *(const s16x8*)(&h_lds[wave][low][32 + quad * 8]);
    s16x8 w0 = *(const s16x8*)(W2q + low * 64 + quad * 8);
    s16x8 w1 = *(const s16x8*)(W2q + low * 64 + 32 + quad * 8);

    f32x4 acc2 = (f32x4){0.f, 0.f, 0.f, 0.f};
    acc2 = __builtin_amdgcn_mfma_f32_16x16x32_bf16(a0, w0, acc2, 0, 0, 0);
    acc2 = __builtin_amdgcn_mfma_f32_16x16x32_bf16(a1, w1, acc2, 0, 0, 0);

    // ---- epilogue 2: alpha2*acc2 + b2, store fp32 ----
    if (low < NOUT) {
        const float bias2 = b2[low];
        #pragma unroll
        for (int r = 0; r < 4; ++r) {
            const int row = m0 + quad * 4 + r;
            out[(size_t)row * NOUT + low] = fmaf(alpha2, acc2[r], bias2);
        }
    }
}

// ---------------------------------------------------------------------------
extern "C" void kernel_launch(void* const* d_in, const int* in_sizes, int n_in,
                              void* d_out, int out_size, void* d_ws, size_t ws_size,
                              hipStream_t stream) {
    const float* x  = (const float*)d_in[0];
    const float* W1 = (const float*)d_in[1];
    const float* b1 = (const float*)d_in[2];
    const float* W2 = (const float*)d_in[3];
    const float* b2 = (const float*)d_in[4];
    float* out = (float*)d_out;

    const int nrows = in_sizes[0] / K1;   // 65536

    // ws layout (all 64B-aligned):
    //   [0]      p1[64] doubles      (512B)
    //   [512]    psm[64] doubles     (512B)
    //   [1024]   pcn[64] doubles     (512B)
    //   [1536]   p2, a2 doubles      (64B block)
    //   [2048]   W1q [64*800] ushort (100KB)
    //   then     W2q [16*64] ushort
    char* base = (char*)d_ws;
    double* p1  = (double*)(base);
    double* psm = (double*)(base + 512);
    double* pcn = (double*)(base + 1024);
    double* p2  = (double*)(base + 1536);
    double* a2  = (double*)(base + 1544);
    unsigned short* W1q = (unsigned short*)(base + 2048);
    unsigned short* W2q = W1q + NHID * K1_PAD;

    tern_sum_kernel<<<64, 256, 0, stream>>>(W1, W2, p1, p2);
    tern_quant_kernel<<<64, 256, 0, stream>>>(W1, W2, W1q, W2q, p1, p2, psm, pcn, a2);

    const int nblocks = nrows / 64;       // 64 rows per block (16 per wave)
    fused_kernel<<<nblocks, 256, 0, stream>>>(x, b1, b2, (const short*)W1q,
                                              (const short*)W2q, psm, pcn, a2, out);
}